// Round 9
// baseline (838.302 us; speedup 1.0000x reference)
//
#include <hip/hip_runtime.h>
#include <hip/hip_bf16.h>
#include <hip/hip_fp16.h>

#define N_NODES 200000
#define N_EDGES 2500000
#define HID 32
#define BN_EPS 1e-5f

#define BKT_SHIFT 9                      // 512 nodes per bucket
#define BKT_N 512
#define B_BKT ((N_NODES + 511) / 512)    // 391 buckets
#define PAD 16                           // one counter per 64B line
#define CAPB 7680                        // bucket capacity (mean 6395 + 16 sigma)
#define EDGES_PER_BLK 8192
#define NB_SCAT ((N_EDGES + EDGES_PER_BLK - 1) / EDGES_PER_BLK)  // 306

// Padded BN-stats: accumulator for channel j at p[j*16] (64B apart -> own
// TCC line -> atomics parallel across channels).
#define SSTR 16
#define S1SUM 0
#define S1SQ  16
#define L2SUM 32
#define L2SQ  (L2SUM + 32 * SSTR)
#define L3SUM (L2SQ + 32 * SSTR)
#define L3SQ  (L3SUM + 32 * SSTR)

__device__ __forceinline__ void atomAddF(float* p, float v) {
    unsafeAtomicAdd(p, v);   // native global_atomic_add_f32 on gfx950
}

// K0: zero bucket cursors + (padded) stats scratch.
__global__ void k_init(int* __restrict__ bcur16, float* __restrict__ stats) {
    int i = blockIdx.x * blockDim.x + threadIdx.x;
    if (i < B_BKT * PAD) bcur16[i] = 0;
    if (i < 4096) stats[i] = 0.0f;
}

// S1: scatter edges into capacity-padded buckets (dst>>9), PACKED:
// word = (local_dst<<18) | src  (src < 2^18, ld < 2^9). 1024 thr x 8 edges:
// long per-bucket runs (~21 edges) + 16 waves/block; edges register-cached.
__global__ void __launch_bounds__(1024)
k_scatter(const int* __restrict__ ei, int* __restrict__ bcur16,
          unsigned int* __restrict__ ebuf) {
    __shared__ int lh[B_BKT], lbase[B_BKT], lc[B_BKT];
    int t = threadIdx.x;
    if (t < B_BKT) { lh[t] = 0; lc[t] = 0; }
    __syncthreads();
    int base = blockIdx.x * EDGES_PER_BLK;
    int sv[8], dv[8];
#pragma unroll
    for (int k = 0; k < 8; k++) {
        int e = base + k * 1024 + t;
        if (e < N_EDGES) {
            sv[k] = ei[e];
            dv[k] = ei[N_EDGES + e];
            atomicAdd(&lh[dv[k] >> BKT_SHIFT], 1);
        } else dv[k] = -1;
    }
    __syncthreads();
    if (t < B_BKT) lbase[t] = lh[t] ? atomicAdd(&bcur16[t * PAD], lh[t]) : 0;
    __syncthreads();
#pragma unroll
    for (int k = 0; k < 8; k++) {
        if (dv[k] >= 0) {
            int b = dv[k] >> BKT_SHIFT;
            int loc = atomicAdd(&lc[b], 1);
            ebuf[(size_t)b * CAPB + lbase[b] + loc] =
                ((unsigned)(dv[k] & 511) << 18) | (unsigned)sv[k];
        }
    }
}

// S2: one block (512 thr) per bucket. Degree histogram -> wave-shuffle
// exclusive scan -> rowbeg/cnt/norm/xp -> CSR placement (single-writer
// region -> dense lines).
__global__ void __launch_bounds__(512)
k_bucket(const unsigned int* __restrict__ ebuf, const int* __restrict__ bcur16,
         const float* __restrict__ x, int* __restrict__ rowbeg,
         int* __restrict__ cntg, float* __restrict__ norm,
         float* __restrict__ xp, int* __restrict__ csrc) {
    __shared__ int hist[512], rbase[512];
    __shared__ int wsum[8];
    int b = blockIdx.x;
    int t = threadIdx.x;
    int lane = t & 63, wv = t >> 6;   // 8 waves
    int count = bcur16[b * PAD];
    size_t ebase = (size_t)b * CAPB;
    int nbase = b << BKT_SHIFT;
    hist[t] = 0;
    __syncthreads();
    for (int i = t; i < count; i += 512)
        atomicAdd(&hist[ebuf[ebase + i] >> 18], 1);
    __syncthreads();
    int v = hist[t];
    int val = v;
#pragma unroll
    for (int off = 1; off < 64; off <<= 1) {
        int nn = __shfl_up(val, off);
        if (lane >= off) val += nn;
    }
    if (lane == 63) wsum[wv] = val;
    __syncthreads();
    if (t < 8) {
        int wval = wsum[t];
        int wincl = wval;
#pragma unroll
        for (int off = 1; off < 8; off <<= 1) {
            int nn = __shfl_up(wincl, off, 8);
            if (t >= off) wincl += nn;
        }
        wsum[t] = wincl - wval;
    }
    __syncthreads();
    int excl = (val - v) + wsum[wv];
    int rb = b * CAPB + excl;
    rbase[t] = rb;
    int n = nbase + t;
    if (n < N_NODES) {
        rowbeg[n] = rb;
        cntg[n] = v;
        float nm = rsqrtf((float)v + 1.0f);
        norm[n] = nm;
        xp[n] = x[n] * nm;
    }
    __syncthreads();
    hist[t] = 0;   // reuse as placement cursors
    __syncthreads();
    for (int i = t; i < count; i += 512) {
        unsigned int w = ebuf[ebase + i];
        int ld = w >> 18;
        int loc = atomicAdd(&hist[ld], 1);
        csrc[rbase[ld] + loc] = (int)(w & 0x3FFFFu);
    }
}

// K5: layer-1 scalar gather s[n] = norm[n]*(xp[n] + sum xp[src]); writes
// packed sn2[n] = {s, norm}; fused scalar stats (2 padded atomics/block).
__global__ void __launch_bounds__(256)
k_gather1(const int* __restrict__ rowbeg, const int* __restrict__ cntg,
          const int* __restrict__ csrc, const float* __restrict__ xp,
          const float* __restrict__ norm, float2* __restrict__ sn2,
          float* __restrict__ stats) {
    __shared__ float ls[256], lq[256];
    int n = blockIdx.x * blockDim.x + threadIdx.x;
    float val = 0.f;
    if (n < N_NODES) {
        int beg = rowbeg[n], dg = cntg[n];
        float acc = xp[n];
        for (int i = 0; i < dg; i++) acc += xp[csrc[beg + i]];
        float nm = norm[n];
        val = nm * acc;
        sn2[n] = make_float2(val, nm);
    }
    ls[threadIdx.x] = val; lq[threadIdx.x] = val * val;
    __syncthreads();
    for (int off = 128; off; off >>= 1) {
        if (threadIdx.x < (unsigned)off) {
            ls[threadIdx.x] += ls[threadIdx.x + off];
            lq[threadIdx.x] += lq[threadIdx.x + off];
        }
        __syncthreads();
    }
    if (threadIdx.x == 0) {
        atomAddF(&stats[S1SUM], ls[0]);
        atomAddF(&stats[S1SQ], lq[0]);
    }
}

// K6: EDGE-CENTRIC fused layer-2. One block per 512-node bucket; 64KB LDS
// z-accumulator. Rank-1 algebra: y1[m]=relu(a_j*s_m+s_j) is a function of
// scalar s_m, so z[n][j] = nm_n*y1[n] + sum_src nm_src*y1[src] accumulates
// edge-centrically: stream the bucket's CONTIGUOUS ebuf segment (independent
// iterations — no dependent-load chain like r8's fusedL2), LDS-atomic into
// z[ld][j] (lane j -> bank j: 2-way/wave = free). Then B = norm*(z@W2) from
// LDS + fused block-level BN stats (391 padded atomics/line).
__global__ void __launch_bounds__(512)
k_aggL2(const unsigned int* __restrict__ ebuf, const int* __restrict__ bcur16,
        const float2* __restrict__ sn2, const float* __restrict__ stats,
        const float* __restrict__ W1, const float* __restrict__ g1,
        const float* __restrict__ be1, const float* __restrict__ W2,
        float* __restrict__ B, float* __restrict__ sumO,
        float* __restrict__ sumsqO) {
    __shared__ float z[BKT_N * 32];   // exactly 64 KB
    int b = blockIdx.x, t = threadIdx.x;
    int g = t >> 5, j = t & 31;       // 16 edge-groups x 32 channels
    int count = bcur16[b * PAD];
    size_t ebase = (size_t)b * CAPB;
    int nbase = b << BKT_SHIFT;
    // per-thread rank-1 BN coefficients for channel j (broadcast loads)
    float m   = stats[S1SUM] * (1.0f / N_NODES);
    float var = stats[S1SQ] * (1.0f / N_NODES) - m * m;
    float w1j = W1[j];
    float a = g1[j] * w1j * rsqrtf(var * w1j * w1j + BN_EPS);
    float sv = be1[j] - m * a;
    // self-loop init (also zeroes rows of invalid tail nodes)
#pragma unroll
    for (int rep = 0; rep < BKT_N / 16; rep++) {
        int nl = rep * 16 + g;
        int n = nbase + nl;
        float val = 0.f;
        if (n < N_NODES) {
            float2 p = sn2[n];
            val = p.y * fmaxf(a * p.x + sv, 0.f);
        }
        z[nl * 32 + j] = val;
    }
    __syncthreads();
    // edge accumulation: 16 groups, stride 16, unroll x2 for load ILP
    int i = g;
    for (; i + 16 < count; i += 32) {
        unsigned w0 = ebuf[ebase + i];
        unsigned w2w = ebuf[ebase + i + 16];
        float2 q0 = sn2[w0 & 0x3FFFFu];
        float2 q1 = sn2[w2w & 0x3FFFFu];
        float v0 = q0.y * fmaxf(a * q0.x + sv, 0.f);
        float v1 = q1.y * fmaxf(a * q1.x + sv, 0.f);
        atomicAdd(&z[(w0 >> 18) * 32 + j], v0);
        atomicAdd(&z[(w2w >> 18) * 32 + j], v1);
    }
    if (i < count) {
        unsigned w0 = ebuf[ebase + i];
        float2 q0 = sn2[w0 & 0x3FFFFu];
        atomicAdd(&z[(w0 >> 18) * 32 + j], q0.y * fmaxf(a * q0.x + sv, 0.f));
    }
    __syncthreads();
    // matmul: register-cache W2 column j, each thread does 32 nodes
    float wcol[32];
#pragma unroll
    for (int k = 0; k < 32; k++) wcol[k] = W2[k * 32 + j];
    float ssum = 0.f, ssq = 0.f;
    for (int rep = 0; rep < BKT_N / 16; rep++) {
        int nl = rep * 16 + g;
        int n = nbase + nl;
        const float4* zr = (const float4*)(z + nl * 32);
        float acc = 0.f;
#pragma unroll
        for (int q = 0; q < 8; q++) {
            float4 zz = zr[q];   // broadcast across the 32-lane group
            acc += zz.x * wcol[4 * q] + zz.y * wcol[4 * q + 1] +
                   zz.z * wcol[4 * q + 2] + zz.w * wcol[4 * q + 3];
        }
        if (n < N_NODES) {
            float bv = acc * sn2[n].y;
            B[n * 32 + j] = bv;
            ssum += bv; ssq += bv * bv;
        }
    }
    // fused layer-2 BN stats: block-reduce via z (free after matmul)
    __syncthreads();
    z[t] = ssum; z[512 + t] = ssq;
    __syncthreads();
    if (t < 32) {
        float s = 0.f, q = 0.f;
        for (int gg = 0; gg < 16; gg++) {
            s += z[gg * 32 + t];
            q += z[512 + gg * 32 + t];
        }
        atomAddF(&sumO[t * SSTR], s);
        atomAddF(&sumsqO[t * SSTR], q);
    }
}

// K9: per-channel sum/sumsq, PADDED accumulators (64B apart; 512/line).
__global__ void k_stats32(const float* __restrict__ agg, float* __restrict__ sum,
                          float* __restrict__ sumsq) {
    int j = threadIdx.x & 31;
    int rl = threadIdx.x >> 5;   // 0..7
    float a = 0.f, q = 0.f;
    for (int n = blockIdx.x * 8 + rl; n < N_NODES; n += gridDim.x * 8) {
        float v = agg[n * 32 + j];
        a += v; q += v * v;
    }
    __shared__ float ls[8][32], lq[8][32];
    ls[rl][j] = a; lq[rl][j] = q;
    __syncthreads();
    for (int off = 4; off; off >>= 1) {
        if (rl < off) { ls[rl][j] += ls[rl + off][j]; lq[rl][j] += lq[rl + off][j]; }
        __syncthreads();
    }
    if (rl == 0) { atomAddF(&sum[j * SSTR], ls[0][j]); atomAddF(&sumsq[j * SSTR], lq[0][j]); }
}

// K10: fused BN+ReLU + y@W3, pre-scaled by norm[n]. Reads B fp32, writes A16.
__global__ void __launch_bounds__(256)
k_fusedB(const float* __restrict__ norm, const float* __restrict__ sum,
         const float* __restrict__ sumsq, const float* __restrict__ g,
         const float* __restrict__ be, const float* __restrict__ W,
         const float* __restrict__ aggIn, __half* __restrict__ hOut) {
    __shared__ float wl[1024];
    __shared__ float sc[32], sh[32];
    __shared__ float y[8][33];
    int tid = threadIdx.x;
    for (int i = tid; i < 1024; i += 256) wl[i] = W[i];
    if (tid < 32) {
        float m   = sum[tid * SSTR] * (1.0f / N_NODES);
        float var = sumsq[tid * SSTR] * (1.0f / N_NODES) - m * m;
        float scj = g[tid] * rsqrtf(var + BN_EPS);
        sc[tid] = scj;
        sh[tid] = be[tid] - m * scj;
    }
    int nl = tid >> 5, j = tid & 31;
    int n = blockIdx.x * 8 + nl;
    __syncthreads();
    float yv = 0.f;
    if (n < N_NODES) yv = fmaxf(sc[j] * aggIn[n * 32 + j] + sh[j], 0.f);
    y[nl][j] = yv;
    __syncthreads();
    if (n < N_NODES) {
        float acc = 0.f;
#pragma unroll
        for (int k = 0; k < 32; k++) acc += y[nl][k] * wl[k * 32 + j];
        hOut[n * 32 + j] = __float2half(acc * norm[n]);
    }
}

__device__ __forceinline__ void load8h(const __half* p, float2& f0, float2& f1,
                                       float2& f2, float2& f3) {
    float4 raw = *(const float4*)p;              // one 16B load
    const __half2* h = (const __half2*)&raw;
    f0 = __half22float2(h[0]);
    f1 = __half22float2(h[1]);
    f2 = __half22float2(h[2]);
    f3 = __half22float2(h[3]);
}

// K8b: CSR gather-aggregate, f16 messages. 4 thr/node, 8 ch each, one node
// per thread-group (max TLP), NO epilogue. Grid: 3125 x 64.
__global__ void __launch_bounds__(256)
k_gatherH(const int* __restrict__ rowbeg, const int* __restrict__ cntg,
          const int* __restrict__ csrc, const __half* __restrict__ A,
          const float* __restrict__ norm, float* __restrict__ B) {
    int tid = threadIdx.x;
    int n = blockIdx.x * 64 + (tid >> 2);
    if (n >= N_NODES) return;
    int c8 = (tid & 3) * 8;
    int beg = rowbeg[n], dg = cntg[n];
    float2 a0, a1, a2, a3;
    load8h(A + n * 32 + c8, a0, a1, a2, a3);   // self-loop
    int i = 0;
    for (; i + 1 < dg; i += 2) {
        int e0 = csrc[beg + i], e1 = csrc[beg + i + 1];
        float2 b0, b1, b2, b3, c0, c1, c2, c3;
        load8h(A + e0 * 32 + c8, b0, b1, b2, b3);
        load8h(A + e1 * 32 + c8, c0, c1, c2, c3);
        a0.x += b0.x + c0.x; a0.y += b0.y + c0.y;
        a1.x += b1.x + c1.x; a1.y += b1.y + c1.y;
        a2.x += b2.x + c2.x; a2.y += b2.y + c2.y;
        a3.x += b3.x + c3.x; a3.y += b3.y + c3.y;
    }
    if (i < dg) {
        float2 b0, b1, b2, b3;
        load8h(A + csrc[beg + i] * 32 + c8, b0, b1, b2, b3);
        a0.x += b0.x; a0.y += b0.y; a1.x += b1.x; a1.y += b1.y;
        a2.x += b2.x; a2.y += b2.y; a3.x += b3.x; a3.y += b3.y;
    }
    float nm = norm[n];
    float4 o0 = make_float4(a0.x * nm, a0.y * nm, a1.x * nm, a1.y * nm);
    float4 o1 = make_float4(a2.x * nm, a2.y * nm, a3.x * nm, a3.y * nm);
    *(float4*)(B + n * 32 + c8) = o0;
    *(float4*)(B + n * 32 + c8 + 4) = o1;
}

// K11: final BN+ReLU + dot with fcW + fcb. Reads padded stats.
__global__ void __launch_bounds__(256)
k_final(const float* __restrict__ aggIn, const float* __restrict__ sum,
        const float* __restrict__ sumsq, const float* __restrict__ g,
        const float* __restrict__ be, const float* __restrict__ fcW,
        const float* __restrict__ fcb, float* __restrict__ out) {
    __shared__ float sc[32], sh[32], fw[32];
    int tid = threadIdx.x;
    if (tid < 32) {
        float m   = sum[tid * SSTR] * (1.0f / N_NODES);
        float var = sumsq[tid * SSTR] * (1.0f / N_NODES) - m * m;
        float scj = g[tid] * rsqrtf(var + BN_EPS);
        sc[tid] = scj;
        sh[tid] = be[tid] - m * scj;
        fw[tid] = fcW[tid];
    }
    __syncthreads();
    int nl = tid >> 5, j = tid & 31;
    int n = blockIdx.x * 8 + nl;
    float v = 0.f;
    if (n < N_NODES) v = fmaxf(sc[j] * aggIn[n * 32 + j] + sh[j], 0.f) * fw[j];
    for (int off = 16; off; off >>= 1) v += __shfl_down(v, off, 32);
    if (j == 0 && n < N_NODES) out[n] = v + fcb[0];
}

extern "C" void kernel_launch(void* const* d_in, const int* in_sizes, int n_in,
                              void* d_out, int out_size, void* d_ws, size_t ws_size,
                              hipStream_t stream) {
    const float* x   = (const float*)d_in[0];
    const int*   ei  = (const int*)d_in[1];
    // d_in[2] edge_attr: unused by the reference
    const float* W1  = (const float*)d_in[3];
    // b1/b2/b3 cancel under training-mode BN
    const float* g1  = (const float*)d_in[5];
    const float* be1 = (const float*)d_in[6];
    const float* W2  = (const float*)d_in[7];
    const float* g2  = (const float*)d_in[9];
    const float* be2 = (const float*)d_in[10];
    const float* W3  = (const float*)d_in[11];
    const float* g3  = (const float*)d_in[13];
    const float* be3 = (const float*)d_in[14];
    const float* fcW = (const float*)d_in[15];
    const float* fcb = (const float*)d_in[16];
    float* out = (float*)d_out;

    // Workspace. Region0 [0, 12.8M) time-multiplexed (strictly ordered):
    //   ebuf u32[391*7680] = 12.0MB (last read k_aggL2)
    //   A16 f16 N*32 = 12.8MB (k_fusedB -> k_gatherH)
    char* base = (char*)d_ws;
    __half*       A16  = (__half*)base;
    unsigned int* ebuf = (unsigned int*)base;
    float*  B      = (float*)(base + (size_t)N_NODES * 32 * 2);   // 12.8M
    int*    csrc   = (int*)(base + (size_t)N_NODES * 32 * 6);     // +25.6M
    float2* sn2    = (float2*)(csrc + (size_t)B_BKT * CAPB);
    int*    rowbeg = (int*)(sn2 + N_NODES);
    int*    cntg   = rowbeg + N_NODES;
    float*  norm   = (float*)(cntg + N_NODES);
    float*  xp     = norm + N_NODES;
    float*  stats  = xp + N_NODES;                 // [4096]
    int*    bcur16 = (int*)(stats + 4096);         // [B_BKT*16]

    const int nbN = (N_NODES + 255) / 256;
    const int nbZ = (B_BKT * PAD + 255) / 256;     // 6256 -> covers 4096 too
    const int nbNode8 = (N_NODES + 7) / 8;

    k_init   <<<nbZ, 256, 0, stream>>>(bcur16, stats);
    k_scatter<<<NB_SCAT, 1024, 0, stream>>>(ei, bcur16, ebuf);
    k_bucket <<<B_BKT, 512, 0, stream>>>(ebuf, bcur16, x, rowbeg, cntg, norm, xp, csrc);
    k_gather1<<<nbN, 256, 0, stream>>>(rowbeg, cntg, csrc, xp, norm, sn2, stats);
    k_aggL2  <<<B_BKT, 512, 0, stream>>>(ebuf, bcur16, sn2, stats, W1, g1, be1,
                                         W2, B, stats + L2SUM, stats + L2SQ);
    k_fusedB <<<nbNode8, 256, 0, stream>>>(norm, stats + L2SUM, stats + L2SQ,
                                           g2, be2, W3, B, A16);
    k_gatherH<<<N_NODES / 64, 256, 0, stream>>>(rowbeg, cntg, csrc, A16, norm, B);
    k_stats32<<<512, 256, 0, stream>>>(B, stats + L3SUM, stats + L3SQ);
    k_final  <<<nbNode8, 256, 0, stream>>>(B, stats + L3SUM, stats + L3SQ,
                                           g3, be3, fcW, fcb, out);
}

// Round 10
// 397.441 us; speedup vs baseline: 2.1093x; 2.1093x over previous
//
#include <hip/hip_runtime.h>
#include <hip/hip_bf16.h>
#include <hip/hip_fp16.h>

#define N_NODES 200000
#define N_EDGES 2500000
#define HID 32
#define BN_EPS 1e-5f

#define BKT_SHIFT 10                     // 1024 nodes per bucket
#define B_BKT ((N_NODES + 1023) / 1024)  // 196 buckets
#define PAD 16                           // one counter per 64B line
#define CAPB 14336                       // bucket capacity (mean 12800 + 13.6 sigma)
#define EDGES_PER_BLK 8192
#define NB_SCAT ((N_EDGES + EDGES_PER_BLK - 1) / EDGES_PER_BLK)  // 306

// Padded BN-stats: accumulator for channel j at p[j*16] (64B apart -> own
// TCC line -> atomics parallel across channels).
#define SSTR 16
#define S1SUM 0
#define S1SQ  16
#define L2SUM 32
#define L2SQ  (L2SUM + 32 * SSTR)
#define L3SUM (L2SQ + 32 * SSTR)
#define L3SQ  (L3SUM + 32 * SSTR)

__device__ __forceinline__ void atomAddF(float* p, float v) {
    unsafeAtomicAdd(p, v);   // native global_atomic_add_f32 on gfx950
}

// K0: zero bucket cursors + (padded) stats scratch.
__global__ void k_init(int* __restrict__ bcur16, float* __restrict__ stats) {
    int i = blockIdx.x * blockDim.x + threadIdx.x;
    if (i < B_BKT * PAD) bcur16[i] = 0;
    if (i < 4096) stats[i] = 0.0f;
}

// S1: scatter edges into capacity-padded buckets (dst>>10), PACKED:
// word = (local_dst<<18) | src  (src < 2^18). 1024 thr x 8 edges: long
// per-bucket runs (~42 edges) + 16 waves/block; edges register-cached.
// [r7-proven form — r4 showed small blocks fragment runs, r9 showed 391
//  buckets at 512thr is slower than 196 at 1024thr]
__global__ void __launch_bounds__(1024)
k_scatter(const int* __restrict__ ei, int* __restrict__ bcur16,
          unsigned int* __restrict__ ebuf) {
    __shared__ int lh[B_BKT], lbase[B_BKT], lc[B_BKT];
    int t = threadIdx.x;
    if (t < B_BKT) { lh[t] = 0; lc[t] = 0; }
    __syncthreads();
    int base = blockIdx.x * EDGES_PER_BLK;
    int sv[8], dv[8];
#pragma unroll
    for (int k = 0; k < 8; k++) {
        int e = base + k * 1024 + t;
        if (e < N_EDGES) {
            sv[k] = ei[e];
            dv[k] = ei[N_EDGES + e];
            atomicAdd(&lh[dv[k] >> BKT_SHIFT], 1);
        } else dv[k] = -1;
    }
    __syncthreads();
    if (t < B_BKT) lbase[t] = lh[t] ? atomicAdd(&bcur16[t * PAD], lh[t]) : 0;
    __syncthreads();
#pragma unroll
    for (int k = 0; k < 8; k++) {
        if (dv[k] >= 0) {
            int b = dv[k] >> BKT_SHIFT;
            int loc = atomicAdd(&lc[b], 1);
            ebuf[(size_t)b * CAPB + lbase[b] + loc] =
                ((unsigned)(dv[k] & 1023) << 18) | (unsigned)sv[k];
        }
    }
}

// S2: one block (1024 thr) per bucket. Degree histogram -> wave-shuffle
// exclusive scan -> rowbeg/cnt/norm/xp -> CSR placement. [r7-proven form]
__global__ void __launch_bounds__(1024)
k_bucket(const unsigned int* __restrict__ ebuf, const int* __restrict__ bcur16,
         const float* __restrict__ x, int* __restrict__ rowbeg,
         int* __restrict__ cntg, float* __restrict__ norm,
         float* __restrict__ xp, int* __restrict__ csrc) {
    __shared__ int hist[1024], rbase[1024];
    __shared__ int wsum[16];
    int b = blockIdx.x;
    int t = threadIdx.x;
    int lane = t & 63, wv = t >> 6;
    int count = bcur16[b * PAD];
    size_t ebase = (size_t)b * CAPB;
    int nbase = b << BKT_SHIFT;
    hist[t] = 0;
    __syncthreads();
    for (int i = t; i < count; i += 1024)
        atomicAdd(&hist[ebuf[ebase + i] >> 18], 1);
    __syncthreads();
    int v = hist[t];
    int val = v;
#pragma unroll
    for (int off = 1; off < 64; off <<= 1) {
        int nn = __shfl_up(val, off);
        if (lane >= off) val += nn;
    }
    if (lane == 63) wsum[wv] = val;
    __syncthreads();
    if (t < 16) {
        int wval = wsum[t];
        int wincl = wval;
#pragma unroll
        for (int off = 1; off < 16; off <<= 1) {
            int nn = __shfl_up(wincl, off, 16);
            if (t >= off) wincl += nn;
        }
        wsum[t] = wincl - wval;
    }
    __syncthreads();
    int excl = (val - v) + wsum[wv];
    int rb = b * CAPB + excl;
    rbase[t] = rb;
    int n = nbase + t;
    if (n < N_NODES) {
        rowbeg[n] = rb;
        cntg[n] = v;
        float nm = rsqrtf((float)v + 1.0f);
        norm[n] = nm;
        xp[n] = x[n] * nm;
    }
    __syncthreads();
    hist[t] = 0;   // reuse as placement cursors
    __syncthreads();
    for (int i = t; i < count; i += 1024) {
        unsigned int w = ebuf[ebase + i];
        int ld = w >> 18;
        int loc = atomicAdd(&hist[ld], 1);
        csrc[rbase[ld] + loc] = (int)(w & 0x3FFFFu);
    }
}

// K5: layer-1 scalar gather s[n] = norm[n]*(xp[n] + sum xp[src]); fused
// scalar stats (2 padded atomics/block: benign). [r6/r7-proven form]
__global__ void __launch_bounds__(256)
k_gather1(const int* __restrict__ rowbeg, const int* __restrict__ cntg,
          const int* __restrict__ csrc, const float* __restrict__ xp,
          const float* __restrict__ norm, float* __restrict__ s,
          float* __restrict__ stats) {
    __shared__ float ls[256], lq[256];
    int n = blockIdx.x * blockDim.x + threadIdx.x;
    float val = 0.f;
    if (n < N_NODES) {
        int beg = rowbeg[n], dg = cntg[n];
        float acc = xp[n];
        for (int i = 0; i < dg; i++) acc += xp[csrc[beg + i]];
        val = norm[n] * acc;
        s[n] = val;
    }
    ls[threadIdx.x] = val; lq[threadIdx.x] = val * val;
    __syncthreads();
    for (int off = 128; off; off >>= 1) {
        if (threadIdx.x < (unsigned)off) {
            ls[threadIdx.x] += ls[threadIdx.x + off];
            lq[threadIdx.x] += lq[threadIdx.x + off];
        }
        __syncthreads();
    }
    if (threadIdx.x == 0) {
        atomAddF(&stats[S1SUM], ls[0]);
        atomAddF(&stats[S1SQ], lq[0]);
    }
}

// K7: fused layer-1 BN+ReLU (rank-1 form) + y1@W2, pre-scaled by norm[n].
// Writes A32 fp32 (layer-2 messages full precision: r4 showed f16 here
// leaves only 0.6% absmax margin). [r6-proven form]
__global__ void __launch_bounds__(256)
k_fusedA(const float* __restrict__ s, const float* __restrict__ norm,
         const float* __restrict__ stats, const float* __restrict__ W1,
         const float* __restrict__ g1, const float* __restrict__ be1,
         const float* __restrict__ W2, float* __restrict__ A32) {
    __shared__ float w2[1024];
    __shared__ float aj[32], sj[32];
    __shared__ float y[8][33];
    int tid = threadIdx.x;
    for (int i = tid; i < 1024; i += 256) w2[i] = W2[i];
    if (tid < 32) {
        float m   = stats[S1SUM] * (1.0f / N_NODES);
        float var = stats[S1SQ] * (1.0f / N_NODES) - m * m;
        float w = W1[tid];
        float a = g1[tid] * w * rsqrtf(var * w * w + BN_EPS);
        aj[tid] = a;
        sj[tid] = be1[tid] - m * a;
    }
    int nl = tid >> 5, j = tid & 31;
    int n = blockIdx.x * 8 + nl;
    __syncthreads();
    float sv = (n < N_NODES) ? s[n] : 0.f;
    y[nl][j] = fmaxf(aj[j] * sv + sj[j], 0.f);
    __syncthreads();
    if (n < N_NODES) {
        float acc = 0.f;
#pragma unroll
        for (int k = 0; k < 32; k++) acc += y[nl][k] * w2[k * 32 + j];
        A32[n * 32 + j] = acc * norm[n];
    }
}

// K8a: CSR gather-aggregate, fp32 messages. 8 thr/node, float4 each, one
// node per group (max TLP — 25k waves; r7/r8/r9 proved TLP > epilogue
// convenience for this latency-bound gather). NO epilogue. [r6: 54 µs]
__global__ void __launch_bounds__(256)
k_gatherF(const int* __restrict__ rowbeg, const int* __restrict__ cntg,
          const int* __restrict__ csrc, const float* __restrict__ A,
          const float* __restrict__ norm, float* __restrict__ B) {
    int tid = threadIdx.x;
    int n = blockIdx.x * 32 + (tid >> 3);
    if (n >= N_NODES) return;
    int c = (tid & 7) * 4;
    int beg = rowbeg[n], dg = cntg[n];
    float4 acc = *(const float4*)(A + n * 32 + c);    // self-loop
    int i = 0;
    for (; i + 1 < dg; i += 2) {
        int e0 = csrc[beg + i], e1 = csrc[beg + i + 1];
        float4 v0 = *(const float4*)(A + e0 * 32 + c);
        float4 v1 = *(const float4*)(A + e1 * 32 + c);
        acc.x += v0.x + v1.x; acc.y += v0.y + v1.y;
        acc.z += v0.z + v1.z; acc.w += v0.w + v1.w;
    }
    if (i < dg) {
        float4 v = *(const float4*)(A + csrc[beg + i] * 32 + c);
        acc.x += v.x; acc.y += v.y; acc.z += v.z; acc.w += v.w;
    }
    float nm = norm[n];
    float4 o = make_float4(acc.x * nm, acc.y * nm, acc.z * nm, acc.w * nm);
    *(float4*)(B + n * 32 + c) = o;
}

// K9: per-channel sum/sumsq, PADDED accumulators (64B apart; 512/line —
// r5 showed unpadded same-line atomics are a ~1000x throughput cliff).
__global__ void k_stats32(const float* __restrict__ agg, float* __restrict__ sum,
                          float* __restrict__ sumsq) {
    int j = threadIdx.x & 31;
    int rl = threadIdx.x >> 5;   // 0..7
    float a = 0.f, q = 0.f;
    for (int n = blockIdx.x * 8 + rl; n < N_NODES; n += gridDim.x * 8) {
        float v = agg[n * 32 + j];
        a += v; q += v * v;
    }
    __shared__ float ls[8][32], lq[8][32];
    ls[rl][j] = a; lq[rl][j] = q;
    __syncthreads();
    for (int off = 4; off; off >>= 1) {
        if (rl < off) { ls[rl][j] += ls[rl + off][j]; lq[rl][j] += lq[rl + off][j]; }
        __syncthreads();
    }
    if (rl == 0) { atomAddF(&sum[j * SSTR], ls[0][j]); atomAddF(&sumsq[j * SSTR], lq[0][j]); }
}

// K10: fused BN+ReLU + y@W3, pre-scaled by norm[n]. Reads B fp32, writes A16
// (f16 layer-3 messages: fresh rounding only, absmax 0.0078 — 6x margin).
__global__ void __launch_bounds__(256)
k_fusedB(const float* __restrict__ norm, const float* __restrict__ sum,
         const float* __restrict__ sumsq, const float* __restrict__ g,
         const float* __restrict__ be, const float* __restrict__ W,
         const float* __restrict__ aggIn, __half* __restrict__ hOut) {
    __shared__ float wl[1024];
    __shared__ float sc[32], sh[32];
    __shared__ float y[8][33];
    int tid = threadIdx.x;
    for (int i = tid; i < 1024; i += 256) wl[i] = W[i];
    if (tid < 32) {
        float m   = sum[tid * SSTR] * (1.0f / N_NODES);
        float var = sumsq[tid * SSTR] * (1.0f / N_NODES) - m * m;
        float scj = g[tid] * rsqrtf(var + BN_EPS);
        sc[tid] = scj;
        sh[tid] = be[tid] - m * scj;
    }
    int nl = tid >> 5, j = tid & 31;
    int n = blockIdx.x * 8 + nl;
    __syncthreads();
    float yv = 0.f;
    if (n < N_NODES) yv = fmaxf(sc[j] * aggIn[n * 32 + j] + sh[j], 0.f);
    y[nl][j] = yv;
    __syncthreads();
    if (n < N_NODES) {
        float acc = 0.f;
#pragma unroll
        for (int k = 0; k < 32; k++) acc += y[nl][k] * wl[k * 32 + j];
        hOut[n * 32 + j] = __float2half(acc * norm[n]);
    }
}

__device__ __forceinline__ void load8h(const __half* p, float2& f0, float2& f1,
                                       float2& f2, float2& f3) {
    float4 raw = *(const float4*)p;              // one 16B load
    const __half2* h = (const __half2*)&raw;
    f0 = __half22float2(h[0]);
    f1 = __half22float2(h[1]);
    f2 = __half22float2(h[2]);
    f3 = __half22float2(h[3]);
}

// K8b: CSR gather-aggregate, f16 messages. 4 thr/node, 8 ch each, one node
// per group (max TLP — 12.5k waves). NO epilogue. [r6-proven form]
__global__ void __launch_bounds__(256)
k_gatherH(const int* __restrict__ rowbeg, const int* __restrict__ cntg,
          const int* __restrict__ csrc, const __half* __restrict__ A,
          const float* __restrict__ norm, float* __restrict__ B) {
    int tid = threadIdx.x;
    int n = blockIdx.x * 64 + (tid >> 2);
    if (n >= N_NODES) return;
    int c8 = (tid & 3) * 8;
    int beg = rowbeg[n], dg = cntg[n];
    float2 a0, a1, a2, a3;
    load8h(A + n * 32 + c8, a0, a1, a2, a3);   // self-loop
    int i = 0;
    for (; i + 1 < dg; i += 2) {
        int e0 = csrc[beg + i], e1 = csrc[beg + i + 1];
        float2 b0, b1, b2, b3, c0, c1, c2, c3;
        load8h(A + e0 * 32 + c8, b0, b1, b2, b3);
        load8h(A + e1 * 32 + c8, c0, c1, c2, c3);
        a0.x += b0.x + c0.x; a0.y += b0.y + c0.y;
        a1.x += b1.x + c1.x; a1.y += b1.y + c1.y;
        a2.x += b2.x + c2.x; a2.y += b2.y + c2.y;
        a3.x += b3.x + c3.x; a3.y += b3.y + c3.y;
    }
    if (i < dg) {
        float2 b0, b1, b2, b3;
        load8h(A + csrc[beg + i] * 32 + c8, b0, b1, b2, b3);
        a0.x += b0.x; a0.y += b0.y; a1.x += b1.x; a1.y += b1.y;
        a2.x += b2.x; a2.y += b2.y; a3.x += b3.x; a3.y += b3.y;
    }
    float nm = norm[n];
    float4 o0 = make_float4(a0.x * nm, a0.y * nm, a1.x * nm, a1.y * nm);
    float4 o1 = make_float4(a2.x * nm, a2.y * nm, a3.x * nm, a3.y * nm);
    *(float4*)(B + n * 32 + c8) = o0;
    *(float4*)(B + n * 32 + c8 + 4) = o1;
}

// K11: final BN+ReLU + dot with fcW + fcb. Reads padded stats.
__global__ void __launch_bounds__(256)
k_final(const float* __restrict__ aggIn, const float* __restrict__ sum,
        const float* __restrict__ sumsq, const float* __restrict__ g,
        const float* __restrict__ be, const float* __restrict__ fcW,
        const float* __restrict__ fcb, float* __restrict__ out) {
    __shared__ float sc[32], sh[32], fw[32];
    int tid = threadIdx.x;
    if (tid < 32) {
        float m   = sum[tid * SSTR] * (1.0f / N_NODES);
        float var = sumsq[tid * SSTR] * (1.0f / N_NODES) - m * m;
        float scj = g[tid] * rsqrtf(var + BN_EPS);
        sc[tid] = scj;
        sh[tid] = be[tid] - m * scj;
        fw[tid] = fcW[tid];
    }
    __syncthreads();
    int nl = tid >> 5, j = tid & 31;
    int n = blockIdx.x * 8 + nl;
    float v = 0.f;
    if (n < N_NODES) v = fmaxf(sc[j] * aggIn[n * 32 + j] + sh[j], 0.f) * fw[j];
    for (int off = 16; off; off >>= 1) v += __shfl_down(v, off, 32);
    if (j == 0 && n < N_NODES) out[n] = v + fcb[0];
}

extern "C" void kernel_launch(void* const* d_in, const int* in_sizes, int n_in,
                              void* d_out, int out_size, void* d_ws, size_t ws_size,
                              hipStream_t stream) {
    const float* x   = (const float*)d_in[0];
    const int*   ei  = (const int*)d_in[1];
    // d_in[2] edge_attr: unused by the reference
    const float* W1  = (const float*)d_in[3];
    // b1/b2/b3 cancel under training-mode BN
    const float* g1  = (const float*)d_in[5];
    const float* be1 = (const float*)d_in[6];
    const float* W2  = (const float*)d_in[7];
    const float* g2  = (const float*)d_in[9];
    const float* be2 = (const float*)d_in[10];
    const float* W3  = (const float*)d_in[11];
    const float* g3  = (const float*)d_in[13];
    const float* be3 = (const float*)d_in[14];
    const float* fcW = (const float*)d_in[15];
    const float* fcb = (const float*)d_in[16];
    float* out = (float*)d_out;

    // Workspace. Region0 [0, 25.6M) time-multiplexed (strictly ordered):
    //   ebuf u32[196*14336] = 11.2MB  (last read: k_bucket)
    //   A32  fp32 N*32      = 25.6MB  (k_fusedA -> k_gatherF)
    //   A16  f16  N*32      = 12.8MB  (k_fusedB -> k_gatherH; A32 dead by then)
    char* base = (char*)d_ws;
    float*        A32  = (float*)base;
    __half*       A16  = (__half*)base;
    unsigned int* ebuf = (unsigned int*)base;
    float*  B      = (float*)(base + (size_t)N_NODES * 32 * 4);   // +25.6M
    int*    csrc   = (int*)(base + (size_t)N_NODES * 32 * 8);     // +25.6M
    int*    rowbeg = csrc + (size_t)B_BKT * CAPB;                 // 11.2M
    int*    cntg   = rowbeg + N_NODES;
    float*  norm   = (float*)(cntg + N_NODES);
    float*  xp     = norm + N_NODES;
    float*  s      = xp + N_NODES;
    float*  stats  = s + N_NODES;                  // [4096]
    int*    bcur16 = (int*)(stats + 4096);         // [B_BKT*16]

    const int nbN = (N_NODES + 255) / 256;
    const int nbZ = (4096 + 255) / 256;            // covers B_BKT*PAD=3136 too
    const int nbNode8 = (N_NODES + 7) / 8;

    k_init   <<<nbZ, 256, 0, stream>>>(bcur16, stats);
    k_scatter<<<NB_SCAT, 1024, 0, stream>>>(ei, bcur16, ebuf);
    k_bucket <<<B_BKT, 1024, 0, stream>>>(ebuf, bcur16, x, rowbeg, cntg, norm, xp, csrc);
    k_gather1<<<nbN, 256, 0, stream>>>(rowbeg, cntg, csrc, xp, norm, s, stats);
    k_fusedA <<<nbNode8, 256, 0, stream>>>(s, norm, stats, W1, g1, be1, W2, A32);
    k_gatherF<<<N_NODES / 32, 256, 0, stream>>>(rowbeg, cntg, csrc, A32, norm, B);
    k_stats32<<<512, 256, 0, stream>>>(B, stats + L2SUM, stats + L2SQ);
    k_fusedB <<<nbNode8, 256, 0, stream>>>(norm, stats + L2SUM, stats + L2SQ,
                                           g2, be2, W3, B, A16);
    k_gatherH<<<N_NODES / 64, 256, 0, stream>>>(rowbeg, cntg, csrc, A16, norm, B);
    k_stats32<<<512, 256, 0, stream>>>(B, stats + L3SUM, stats + L3SQ);
    k_final  <<<nbNode8, 256, 0, stream>>>(B, stats + L3SUM, stats + L3SQ,
                                           g3, be3, fcW, fcb, out);
}